// Round 3
// baseline (1083.628 us; speedup 1.0000x reference)
//
#include <hip/hip_runtime.h>

#define NEG_SLOPE 0.2f

static __device__ __forceinline__ float u16f(unsigned short u){
  union { unsigned int i; float f; } v; v.i = ((unsigned int)u) << 16; return v.f;
}
static __device__ __forceinline__ unsigned short f2u16(float f){
  union { float f; unsigned int i; } v; v.f = f;
  unsigned int r = (v.i + 0x7FFFu + ((v.i >> 16) & 1u)) >> 16;
  return (unsigned short)r;
}
static __device__ __forceinline__ float wsum(float v){
  #pragma unroll
  for (int o = 32; o > 0; o >>= 1) v += __shfl_xor(v, o, 64);
  return v;
}
static __device__ __forceinline__ float wmaxr(float v){
  #pragma unroll
  for (int o = 32; o > 0; o >>= 1) v = fmaxf(v, __shfl_xor(v, o, 64));
  return v;
}
static __device__ __forceinline__ float lrelu(float e){
  return e >= 0.f ? e : NEG_SLOPE * e;
}

__global__ __launch_bounds__(256) void k_zero(int* __restrict__ p, int nwords){
  int i = blockIdx.x * 256 + threadIdx.x;
  if (i < nwords) p[i] = 0;
}

// ---- layer1 node precompute: xw1 = x @ W1 (bf16 out), alpha_s1/alpha_d1 fp32 [N,4]
__global__ __launch_bounds__(256) void k_gemm1(
    const float* __restrict__ x, const float* __restrict__ W1,
    const float* __restrict__ asrc, const float* __restrict__ adst,
    unsigned short* __restrict__ xw1, float* __restrict__ oas, float* __restrict__ oad,
    int N)
{
  __shared__ float xs[8][128];
  int t = threadIdx.x;
  int base = blockIdx.x * 8;
  {
    int elem = t * 4;
    int r = elem >> 7, c = elem & 127;
    int n = base + r;
    float4 f = make_float4(0.f, 0.f, 0.f, 0.f);
    if (n < N) f = *(const float4*)(x + (size_t)n * 128 + c);
    xs[r][c] = f.x; xs[r][c+1] = f.y; xs[r][c+2] = f.z; xs[r][c+3] = f.w;
  }
  __syncthreads();
  float acc[8] = {0,0,0,0,0,0,0,0};
  for (int k = 0; k < 128; k += 4){
    float w0 = W1[(k+0)*256 + t];
    float w1 = W1[(k+1)*256 + t];
    float w2 = W1[(k+2)*256 + t];
    float w3 = W1[(k+3)*256 + t];
    #pragma unroll
    for (int r = 0; r < 8; ++r){
      float4 xv = *(const float4*)&xs[r][k];
      acc[r] += xv.x*w0 + xv.y*w1 + xv.z*w2 + xv.w*w3;
    }
  }
  float avs = asrc[t], avd = adst[t];
  int h = t >> 6, lane = t & 63;
  for (int r = 0; r < 8; ++r){
    int n = base + r;
    if (n >= N) break;
    float val = acc[r];
    xw1[(size_t)n*256 + t] = f2u16(val);
    float ps = wsum(val * avs);
    float pd = wsum(val * avd);
    if (lane == 0){ oas[n*4 + h] = ps; oad[n*4 + h] = pd; }
  }
}

// ---- CSR build
__global__ __launch_bounds__(256) void k_hist(const int* __restrict__ ei,
                                              int* __restrict__ count, int E, int ET){
  int i = blockIdx.x * 256 + threadIdx.x;
  if (i >= ET) return;
  int d = (i < E) ? ei[E + i] : (i - E);
  atomicAdd(&count[d], 1);
}

__global__ __launch_bounds__(256) void k_scan1(const int* __restrict__ count,
                                               int* __restrict__ ro, int* __restrict__ bsum, int N){
  __shared__ int sd[256];
  int t = threadIdx.x, b = blockIdx.x, i = b*256 + t;
  int v = (i < N) ? count[i] : 0;
  sd[t] = v; __syncthreads();
  for (int o = 1; o < 256; o <<= 1){
    int x = (t >= o) ? sd[t - o] : 0;
    __syncthreads();
    sd[t] += x;
    __syncthreads();
  }
  if (i < N) ro[i] = sd[t] - v;  // exclusive
  if (t == 255) bsum[b] = sd[255];
}

__global__ __launch_bounds__(256) void k_scan2(int* __restrict__ bsum, int nb){
  __shared__ int sd[256];
  int t = threadIdx.x;
  int v = (t < nb) ? bsum[t] : 0;
  sd[t] = v; __syncthreads();
  for (int o = 1; o < 256; o <<= 1){
    int x = (t >= o) ? sd[t - o] : 0;
    __syncthreads();
    sd[t] += x;
    __syncthreads();
  }
  if (t < nb) bsum[t] = sd[t] - v;  // exclusive
}

__global__ __launch_bounds__(256) void k_scan3(int* __restrict__ ro,
                                               const int* __restrict__ bsum, int N, int ET){
  int b = blockIdx.x, t = threadIdx.x, i = b*256 + t;
  if (i < N) ro[i] += bsum[b];
  if (b == 0 && t == 0) ro[N] = ET;
}

__global__ __launch_bounds__(256) void k_scatter(const int* __restrict__ ei,
                                                 const int* __restrict__ ro,
                                                 int* __restrict__ cursor,
                                                 int* __restrict__ csr, int E, int ET){
  int i = blockIdx.x * 256 + threadIdx.x;
  if (i >= ET) return;
  int s, d;
  if (i < E){ s = ei[i]; d = ei[E + i]; }
  else      { s = i - E; d = i - E; }
  int pos = ro[d] + atomicAdd(&cursor[d], 1);
  csr[pos] = s;
}

// ---- GAT layer 1 edge phase: one wave per dst node, 4 heads x 64ch
__global__ __launch_bounds__(256) void k_edge1(
    const int* __restrict__ ro, const int* __restrict__ cs,
    const unsigned short* __restrict__ xw1,
    const float* __restrict__ pas, const float* __restrict__ pad,
    const float* __restrict__ bias1,
    const float* __restrict__ g1, const float* __restrict__ b1,
    const float* __restrict__ m1, const float* __restrict__ v1,
    unsigned short* __restrict__ h1, int N)
{
  int lane = threadIdx.x & 63;
  int n = blockIdx.x * 4 + (threadIdx.x >> 6);
  if (n >= N) return;
  int beg = ro[n], end = ro[n + 1];
  const float4 adv = *(const float4*)(pad + (size_t)n * 4);

  float mh0 = -1e30f, mh1 = -1e30f, mh2 = -1e30f, mh3 = -1e30f;
  for (int k = beg + lane; k < end; k += 64){
    int s = cs[k];
    float4 a = *(const float4*)(pas + (size_t)s * 4);
    mh0 = fmaxf(mh0, lrelu(a.x + adv.x));
    mh1 = fmaxf(mh1, lrelu(a.y + adv.y));
    mh2 = fmaxf(mh2, lrelu(a.z + adv.z));
    mh3 = fmaxf(mh3, lrelu(a.w + adv.w));
  }
  mh0 = wmaxr(mh0); mh1 = wmaxr(mh1); mh2 = wmaxr(mh2); mh3 = wmaxr(mh3);

  float dh0 = 0.f, dh1 = 0.f, dh2 = 0.f, dh3 = 0.f;
  for (int k = beg + lane; k < end; k += 64){
    int s = cs[k];
    float4 a = *(const float4*)(pas + (size_t)s * 4);
    dh0 += __expf(lrelu(a.x + adv.x) - mh0);
    dh1 += __expf(lrelu(a.y + adv.y) - mh1);
    dh2 += __expf(lrelu(a.z + adv.z) - mh2);
    dh3 += __expf(lrelu(a.w + adv.w) - mh3);
  }
  dh0 = wsum(dh0); dh1 = wsum(dh1); dh2 = wsum(dh2); dh3 = wsum(dh3);

  int head = lane >> 4;
  float mm, dd, aa;
  if      (head == 0){ mm = mh0; dd = dh0; aa = adv.x; }
  else if (head == 1){ mm = mh1; dd = dh1; aa = adv.y; }
  else if (head == 2){ mm = mh2; dd = dh2; aa = adv.z; }
  else               { mm = mh3; dd = dh3; aa = adv.w; }
  float inv = 1.f / (dd + 1e-16f);

  float a0 = 0.f, a1 = 0.f, a2 = 0.f, a3 = 0.f;
  for (int k = beg; k < end; ++k){
    int s = cs[k];
    float e = lrelu(pas[(size_t)s * 4 + head] + aa);
    float w = __expf(e - mm) * inv;
    ushort4 u = *(const ushort4*)(xw1 + (size_t)s * 256 + lane * 4);
    a0 += w * u16f(u.x); a1 += w * u16f(u.y);
    a2 += w * u16f(u.z); a3 += w * u16f(u.w);
  }

  float accv[4] = {a0, a1, a2, a3};
  ushort4 outv;
  unsigned short* po = (unsigned short*)&outv;
  int j0 = lane * 4;
  #pragma unroll
  for (int i = 0; i < 4; ++i){
    int j = j0 + i;
    float o  = accv[i] + bias1[j];
    float sc = g1[j] * rsqrtf(v1[j] + 1e-5f);
    float res = (o - m1[j]) * sc + b1[j];
    po[i] = f2u16(fmaxf(res, 0.f));
  }
  *(ushort4*)(h1 + (size_t)n * 256 + j0) = outv;
}

// ---- layer2 node precompute: xw2 = h1 @ W2 (256->64), alpha scalars
__global__ __launch_bounds__(256) void k_gemm2(
    const unsigned short* __restrict__ h1, const float* __restrict__ W2,
    const float* __restrict__ asrc, const float* __restrict__ adst,
    unsigned short* __restrict__ xw2, float* __restrict__ oas, float* __restrict__ oad,
    int N)
{
  __shared__ float xs[4][8][256];  // 32 KiB
  int t = threadIdx.x, w = t >> 6, j = t & 63;
  int base = blockIdx.x * 32 + w * 8;
  for (int i = 0; i < 8; ++i){
    int e4 = j + i * 64;
    int elem = e4 * 4;
    int r = elem >> 8, c = elem & 255;
    int n = base + r;
    float f0 = 0.f, f1 = 0.f, f2 = 0.f, f3 = 0.f;
    if (n < N){
      ushort4 u = *(const ushort4*)(h1 + (size_t)n * 256 + c);
      f0 = u16f(u.x); f1 = u16f(u.y); f2 = u16f(u.z); f3 = u16f(u.w);
    }
    xs[w][r][c] = f0; xs[w][r][c+1] = f1; xs[w][r][c+2] = f2; xs[w][r][c+3] = f3;
  }
  __syncthreads();
  float acc[8] = {0,0,0,0,0,0,0,0};
  for (int k = 0; k < 256; k += 4){
    float w0 = W2[(k+0)*64 + j];
    float w1 = W2[(k+1)*64 + j];
    float w2 = W2[(k+2)*64 + j];
    float w3 = W2[(k+3)*64 + j];
    #pragma unroll
    for (int r = 0; r < 8; ++r){
      float4 xv = *(const float4*)&xs[w][r][k];
      acc[r] += xv.x*w0 + xv.y*w1 + xv.z*w2 + xv.w*w3;
    }
  }
  float avs = asrc[j], avd = adst[j];
  for (int r = 0; r < 8; ++r){
    int n = base + r;
    if (n >= N) break;
    float val = acc[r];
    xw2[(size_t)n*64 + j] = f2u16(val);
    float ps = wsum(val * avs);
    float pd = wsum(val * avd);
    if (j == 0){ oas[n] = ps; oad[n] = pd; }
  }
}

// ---- GAT layer 2 edge phase + BN + ReLU + pooled atomic add
__global__ __launch_bounds__(256) void k_edge2(
    const int* __restrict__ ro, const int* __restrict__ cs,
    const unsigned short* __restrict__ xw2,
    const float* __restrict__ pas, const float* __restrict__ pad,
    const float* __restrict__ bias2,
    const float* __restrict__ g2, const float* __restrict__ b2,
    const float* __restrict__ m2, const float* __restrict__ v2,
    const int* __restrict__ batch,
    float* __restrict__ pool, float* __restrict__ cnt, int N)
{
  int lane = threadIdx.x & 63;
  int n = blockIdx.x * 4 + (threadIdx.x >> 6);
  if (n >= N) return;
  int beg = ro[n], end = ro[n + 1];
  float adv = pad[n];

  float mh = -1e30f;
  for (int k = beg + lane; k < end; k += 64){
    int s = cs[k];
    mh = fmaxf(mh, lrelu(pas[s] + adv));
  }
  mh = wmaxr(mh);

  float dh = 0.f;
  for (int k = beg + lane; k < end; k += 64){
    int s = cs[k];
    dh += __expf(lrelu(pas[s] + adv) - mh);
  }
  dh = wsum(dh);
  float inv = 1.f / (dh + 1e-16f);

  float acc = 0.f;
  for (int k = beg; k < end; ++k){
    int s = cs[k];
    float e = lrelu(pas[s] + adv);
    float w = __expf(e - mh) * inv;
    acc += w * u16f(xw2[(size_t)s * 64 + lane]);
  }

  float o  = acc + bias2[lane];
  float sc = g2[lane] * rsqrtf(v2[lane] + 1e-5f);
  float res = fmaxf((o - m2[lane]) * sc + b2[lane], 0.f);
  int g = batch[n];
  atomicAdd(&pool[g * 64 + lane], res);
  if (lane == 0) atomicAdd(&cnt[g], 1.0f);
}

// ---- classifier + log_softmax: one wave per graph, fp32 output
__global__ __launch_bounds__(64) void k_final(
    const float* __restrict__ pool, const float* __restrict__ cnt,
    const float* __restrict__ Wc1, const float* __restrict__ bc1,
    const float* __restrict__ Wc2, const float* __restrict__ bc2,
    float* __restrict__ out)
{
  int g = blockIdx.x, c = threadIdx.x;
  __shared__ float gr[64];
  float inv = 1.f / fmaxf(cnt[g], 1.f);
  gr[c] = pool[g * 64 + c] * inv;
  __syncthreads();
  float a = bc1[c];
  for (int k = 0; k < 64; ++k) a += gr[k] * Wc1[k * 64 + c];
  float hc = fmaxf(a, 0.f);
  float p0 = hc * Wc2[c * 2 + 0];
  float p1 = hc * Wc2[c * 2 + 1];
  p0 = wsum(p0); p1 = wsum(p1);
  if (c == 0){
    float l0 = p0 + bc2[0];
    float l1 = p1 + bc2[1];
    float mx = fmaxf(l0, l1);
    float lse = mx + logf(expf(l0 - mx) + expf(l1 - mx));
    out[g * 2 + 0] = l0 - lse;
    out[g * 2 + 1] = l1 - lse;
  }
}

extern "C" void kernel_launch(void* const* d_in, const int* in_sizes, int n_in,
                              void* d_out, int out_size, void* d_ws, size_t ws_size,
                              hipStream_t stream)
{
  const float* x     = (const float*)d_in[0];
  const int*   ei    = (const int*)d_in[1];
  const int*   batch = (const int*)d_in[2];
  const float* W1    = (const float*)d_in[3];
  const float* asrc1 = (const float*)d_in[4];
  const float* adst1 = (const float*)d_in[5];
  const float* bias1 = (const float*)d_in[6];
  const float* bn1g  = (const float*)d_in[7];
  const float* bn1b  = (const float*)d_in[8];
  const float* bn1m  = (const float*)d_in[9];
  const float* bn1v  = (const float*)d_in[10];
  const float* W2    = (const float*)d_in[11];
  const float* asrc2 = (const float*)d_in[12];
  const float* adst2 = (const float*)d_in[13];
  const float* bias2 = (const float*)d_in[14];
  const float* bn2g  = (const float*)d_in[15];
  const float* bn2b  = (const float*)d_in[16];
  const float* bn2m  = (const float*)d_in[17];
  const float* bn2v  = (const float*)d_in[18];
  const float* Wc1   = (const float*)d_in[19];
  const float* bc1   = (const float*)d_in[20];
  const float* Wc2   = (const float*)d_in[21];
  const float* bc2   = (const float*)d_in[22];
  float* out = (float*)d_out;

  const int N  = in_sizes[0] / 128;
  const int E  = in_sizes[1] / 2;
  const int ET = E + N;

  char* p = (char*)d_ws;
  auto take = [&](size_t bytes) -> void* {
    void* q = (void*)p;
    p += ((bytes + 255) & ~(size_t)255);
    return q;
  };
  int*   count  = (int*)  take((size_t)N * 4);
  int*   cursor = (int*)  take((size_t)N * 4);
  float* pool   = (float*)take(64 * 64 * 4);
  float* cnt    = (float*)take(64 * 4);
  size_t zbytes = (size_t)(p - (char*)d_ws);
  int*   ro     = (int*)  take((size_t)(N + 1) * 4);
  int*   bsum   = (int*)  take(1024);
  float* as1    = (float*)take((size_t)N * 16);
  float* ad1    = (float*)take((size_t)N * 16);
  float* as2    = (float*)take((size_t)N * 4);
  float* ad2    = (float*)take((size_t)N * 4);
  unsigned short* xw1 = (unsigned short*)take((size_t)N * 256 * 2);
  unsigned short* h1  = (unsigned short*)take((size_t)N * 256 * 2);
  int*   csr    = (int*)  take((size_t)ET * 4);
  unsigned short* xw2 = xw1;  // alias: xw1 dead after k_edge1, xw2 born in k_gemm2
  (void)count; (void)n_in; (void)ws_size; (void)out_size;

  int zw = (int)(zbytes / 4);
  k_zero<<<dim3((zw + 255) / 256), dim3(256), 0, stream>>>((int*)d_ws, zw);
  k_gemm1<<<dim3((N + 7) / 8), dim3(256), 0, stream>>>(x, W1, asrc1, adst1, xw1, as1, ad1, N);
  k_hist<<<dim3((ET + 255) / 256), dim3(256), 0, stream>>>(ei, count, E, ET);
  int nb = (N + 255) / 256;
  k_scan1<<<dim3(nb), dim3(256), 0, stream>>>(count, ro, bsum, N);
  k_scan2<<<dim3(1), dim3(256), 0, stream>>>(bsum, nb);
  k_scan3<<<dim3(nb), dim3(256), 0, stream>>>(ro, bsum, N, ET);
  k_scatter<<<dim3((ET + 255) / 256), dim3(256), 0, stream>>>(ei, ro, cursor, csr, E, ET);
  k_edge1<<<dim3((N + 3) / 4), dim3(256), 0, stream>>>(ro, csr, xw1, as1, ad1,
                                                       bias1, bn1g, bn1b, bn1m, bn1v, h1, N);
  k_gemm2<<<dim3((N + 31) / 32), dim3(256), 0, stream>>>(h1, W2, asrc2, adst2, xw2, as2, ad2, N);
  k_edge2<<<dim3((N + 3) / 4), dim3(256), 0, stream>>>(ro, csr, xw2, as2, ad2,
                                                       bias2, bn2g, bn2b, bn2m, bn2v,
                                                       batch, pool, cnt, N);
  k_final<<<dim3(64), dim3(64), 0, stream>>>(pool, cnt, Wc1, bc1, Wc2, bc2, out);
}

// Round 4
// 853.935 us; speedup vs baseline: 1.2690x; 1.2690x over previous
//
#include <hip/hip_runtime.h>

#define NEG_SLOPE 0.2f

static __device__ __forceinline__ float u16f(unsigned short u){
  union { unsigned int i; float f; } v; v.i = ((unsigned int)u) << 16; return v.f;
}
static __device__ __forceinline__ unsigned short f2u16(float f){
  union { float f; unsigned int i; } v; v.f = f;
  unsigned int r = (v.i + 0x7FFFu + ((v.i >> 16) & 1u)) >> 16;
  return (unsigned short)r;
}
static __device__ __forceinline__ float wsum(float v){
  #pragma unroll
  for (int o = 32; o > 0; o >>= 1) v += __shfl_xor(v, o, 64);
  return v;
}
static __device__ __forceinline__ float wmaxr(float v){
  #pragma unroll
  for (int o = 32; o > 0; o >>= 1) v = fmaxf(v, __shfl_xor(v, o, 64));
  return v;
}
static __device__ __forceinline__ float lrelu(float e){
  return e >= 0.f ? e : NEG_SLOPE * e;
}

__global__ __launch_bounds__(256) void k_zero(int* __restrict__ p, int nwords){
  int i = blockIdx.x * 256 + threadIdx.x;
  if (i < nwords) p[i] = 0;
}

// ---- layer1 node precompute: xw1 = x @ W1 (bf16 out), alpha_s1/alpha_d1 fp32 [N,4]
__global__ __launch_bounds__(256) void k_gemm1(
    const float* __restrict__ x, const float* __restrict__ W1,
    const float* __restrict__ asrc, const float* __restrict__ adst,
    unsigned short* __restrict__ xw1, float* __restrict__ oas, float* __restrict__ oad,
    int N)
{
  __shared__ float xs[8][128];
  int t = threadIdx.x;
  int base = blockIdx.x * 8;
  {
    int elem = t * 4;
    int r = elem >> 7, c = elem & 127;
    int n = base + r;
    float4 f = make_float4(0.f, 0.f, 0.f, 0.f);
    if (n < N) f = *(const float4*)(x + (size_t)n * 128 + c);
    xs[r][c] = f.x; xs[r][c+1] = f.y; xs[r][c+2] = f.z; xs[r][c+3] = f.w;
  }
  __syncthreads();
  float acc[8] = {0,0,0,0,0,0,0,0};
  for (int k = 0; k < 128; k += 4){
    float w0 = W1[(k+0)*256 + t];
    float w1 = W1[(k+1)*256 + t];
    float w2 = W1[(k+2)*256 + t];
    float w3 = W1[(k+3)*256 + t];
    #pragma unroll
    for (int r = 0; r < 8; ++r){
      float4 xv = *(const float4*)&xs[r][k];
      acc[r] += xv.x*w0 + xv.y*w1 + xv.z*w2 + xv.w*w3;
    }
  }
  float avs = asrc[t], avd = adst[t];
  int h = t >> 6, lane = t & 63;
  for (int r = 0; r < 8; ++r){
    int n = base + r;
    if (n >= N) break;
    float val = acc[r];
    xw1[(size_t)n*256 + t] = f2u16(val);
    float ps = wsum(val * avs);
    float pd = wsum(val * avd);
    if (lane == 0){ oas[n*4 + h] = ps; oad[n*4 + h] = pd; }
  }
}

// ---- CSR build
__global__ __launch_bounds__(256) void k_hist(const int* __restrict__ ei,
                                              int* __restrict__ count, int E, int ET){
  int i = blockIdx.x * 256 + threadIdx.x;
  if (i >= ET) return;
  int d = (i < E) ? ei[E + i] : (i - E);
  atomicAdd(&count[d], 1);
}

__global__ __launch_bounds__(256) void k_scan1(const int* __restrict__ count,
                                               int* __restrict__ ro, int* __restrict__ bsum, int N){
  __shared__ int sd[256];
  int t = threadIdx.x, b = blockIdx.x, i = b*256 + t;
  int v = (i < N) ? count[i] : 0;
  sd[t] = v; __syncthreads();
  for (int o = 1; o < 256; o <<= 1){
    int x = (t >= o) ? sd[t - o] : 0;
    __syncthreads();
    sd[t] += x;
    __syncthreads();
  }
  if (i < N) ro[i] = sd[t] - v;  // exclusive
  if (t == 255) bsum[b] = sd[255];
}

__global__ __launch_bounds__(256) void k_scan2(int* __restrict__ bsum, int nb){
  __shared__ int sd[256];
  int t = threadIdx.x;
  int v = (t < nb) ? bsum[t] : 0;
  sd[t] = v; __syncthreads();
  for (int o = 1; o < 256; o <<= 1){
    int x = (t >= o) ? sd[t - o] : 0;
    __syncthreads();
    sd[t] += x;
    __syncthreads();
  }
  if (t < nb) bsum[t] = sd[t] - v;  // exclusive
}

__global__ __launch_bounds__(256) void k_scan3(int* __restrict__ ro,
                                               const int* __restrict__ bsum, int N, int ET){
  int b = blockIdx.x, t = threadIdx.x, i = b*256 + t;
  if (i < N) ro[i] += bsum[b];
  if (b == 0 && t == 0) ro[N] = ET;
}

__global__ __launch_bounds__(256) void k_scatter(const int* __restrict__ ei,
                                                 const int* __restrict__ ro,
                                                 int* __restrict__ cursor,
                                                 int* __restrict__ csr, int E, int ET){
  int i = blockIdx.x * 256 + threadIdx.x;
  if (i >= ET) return;
  int s, d;
  if (i < E){ s = ei[i]; d = ei[E + i]; }
  else      { s = i - E; d = i - E; }
  int pos = ro[d] + atomicAdd(&cursor[d], 1);
  csr[pos] = s;
}

// ---- GAT layer 1 edge phase: one wave per dst node, 4 heads x 64ch
__global__ __launch_bounds__(256) void k_edge1(
    const int* __restrict__ ro, const int* __restrict__ cs,
    const unsigned short* __restrict__ xw1,
    const float* __restrict__ pas, const float* __restrict__ pad,
    const float* __restrict__ bias1,
    const float* __restrict__ g1, const float* __restrict__ b1,
    const float* __restrict__ m1, const float* __restrict__ v1,
    unsigned short* __restrict__ h1, int N)
{
  int lane = threadIdx.x & 63;
  int n = blockIdx.x * 4 + (threadIdx.x >> 6);
  if (n >= N) return;
  int beg = ro[n], end = ro[n + 1];
  const float4 adv = *(const float4*)(pad + (size_t)n * 4);

  float mh0 = -1e30f, mh1 = -1e30f, mh2 = -1e30f, mh3 = -1e30f;
  for (int k = beg + lane; k < end; k += 64){
    int s = cs[k];
    float4 a = *(const float4*)(pas + (size_t)s * 4);
    mh0 = fmaxf(mh0, lrelu(a.x + adv.x));
    mh1 = fmaxf(mh1, lrelu(a.y + adv.y));
    mh2 = fmaxf(mh2, lrelu(a.z + adv.z));
    mh3 = fmaxf(mh3, lrelu(a.w + adv.w));
  }
  mh0 = wmaxr(mh0); mh1 = wmaxr(mh1); mh2 = wmaxr(mh2); mh3 = wmaxr(mh3);

  float dh0 = 0.f, dh1 = 0.f, dh2 = 0.f, dh3 = 0.f;
  for (int k = beg + lane; k < end; k += 64){
    int s = cs[k];
    float4 a = *(const float4*)(pas + (size_t)s * 4);
    dh0 += __expf(lrelu(a.x + adv.x) - mh0);
    dh1 += __expf(lrelu(a.y + adv.y) - mh1);
    dh2 += __expf(lrelu(a.z + adv.z) - mh2);
    dh3 += __expf(lrelu(a.w + adv.w) - mh3);
  }
  dh0 = wsum(dh0); dh1 = wsum(dh1); dh2 = wsum(dh2); dh3 = wsum(dh3);

  int head = lane >> 4;
  float mm, dd, aa;
  if      (head == 0){ mm = mh0; dd = dh0; aa = adv.x; }
  else if (head == 1){ mm = mh1; dd = dh1; aa = adv.y; }
  else if (head == 2){ mm = mh2; dd = dh2; aa = adv.z; }
  else               { mm = mh3; dd = dh3; aa = adv.w; }
  float inv = 1.f / (dd + 1e-16f);

  float a0 = 0.f, a1 = 0.f, a2 = 0.f, a3 = 0.f;
  for (int k = beg; k < end; ++k){
    int s = cs[k];
    float e = lrelu(pas[(size_t)s * 4 + head] + aa);
    float w = __expf(e - mm) * inv;
    ushort4 u = *(const ushort4*)(xw1 + (size_t)s * 256 + lane * 4);
    a0 += w * u16f(u.x); a1 += w * u16f(u.y);
    a2 += w * u16f(u.z); a3 += w * u16f(u.w);
  }

  float accv[4] = {a0, a1, a2, a3};
  ushort4 outv;
  unsigned short* po = (unsigned short*)&outv;
  int j0 = lane * 4;
  #pragma unroll
  for (int i = 0; i < 4; ++i){
    int j = j0 + i;
    float o  = accv[i] + bias1[j];
    float sc = g1[j] * rsqrtf(v1[j] + 1e-5f);
    float res = (o - m1[j]) * sc + b1[j];
    po[i] = f2u16(fmaxf(res, 0.f));
  }
  *(ushort4*)(h1 + (size_t)n * 256 + j0) = outv;
}

// ---- layer2 node precompute: xw2 = h1 @ W2 (256->64), alpha scalars
__global__ __launch_bounds__(256) void k_gemm2(
    const unsigned short* __restrict__ h1, const float* __restrict__ W2,
    const float* __restrict__ asrc, const float* __restrict__ adst,
    unsigned short* __restrict__ xw2, float* __restrict__ oas, float* __restrict__ oad,
    int N)
{
  __shared__ float xs[4][8][256];  // 32 KiB
  int t = threadIdx.x, w = t >> 6, j = t & 63;
  int base = blockIdx.x * 32 + w * 8;
  for (int i = 0; i < 8; ++i){
    int e4 = j + i * 64;
    int elem = e4 * 4;
    int r = elem >> 8, c = elem & 255;
    int n = base + r;
    float f0 = 0.f, f1 = 0.f, f2 = 0.f, f3 = 0.f;
    if (n < N){
      ushort4 u = *(const ushort4*)(h1 + (size_t)n * 256 + c);
      f0 = u16f(u.x); f1 = u16f(u.y); f2 = u16f(u.z); f3 = u16f(u.w);
    }
    xs[w][r][c] = f0; xs[w][r][c+1] = f1; xs[w][r][c+2] = f2; xs[w][r][c+3] = f3;
  }
  __syncthreads();
  float acc[8] = {0,0,0,0,0,0,0,0};
  for (int k = 0; k < 256; k += 4){
    float w0 = W2[(k+0)*64 + j];
    float w1 = W2[(k+1)*64 + j];
    float w2 = W2[(k+2)*64 + j];
    float w3 = W2[(k+3)*64 + j];
    #pragma unroll
    for (int r = 0; r < 8; ++r){
      float4 xv = *(const float4*)&xs[w][r][k];
      acc[r] += xv.x*w0 + xv.y*w1 + xv.z*w2 + xv.w*w3;
    }
  }
  float avs = asrc[j], avd = adst[j];
  for (int r = 0; r < 8; ++r){
    int n = base + r;
    if (n >= N) break;
    float val = acc[r];
    xw2[(size_t)n*64 + j] = f2u16(val);
    float ps = wsum(val * avs);
    float pd = wsum(val * avd);
    if (j == 0){ oas[n] = ps; oad[n] = pd; }
  }
}

// ---- GAT layer 2 edge phase + BN + ReLU -> h2[n,64] fp32 (no atomics)
__global__ __launch_bounds__(256) void k_edge2(
    const int* __restrict__ ro, const int* __restrict__ cs,
    const unsigned short* __restrict__ xw2,
    const float* __restrict__ pas, const float* __restrict__ pad,
    const float* __restrict__ bias2,
    const float* __restrict__ g2, const float* __restrict__ b2,
    const float* __restrict__ m2, const float* __restrict__ v2,
    float* __restrict__ h2, int N)
{
  int lane = threadIdx.x & 63;
  int n = blockIdx.x * 4 + (threadIdx.x >> 6);
  if (n >= N) return;
  int beg = ro[n], end = ro[n + 1];
  float adv = pad[n];

  float mh = -1e30f;
  for (int k = beg + lane; k < end; k += 64){
    int s = cs[k];
    mh = fmaxf(mh, lrelu(pas[s] + adv));
  }
  mh = wmaxr(mh);

  float dh = 0.f;
  for (int k = beg + lane; k < end; k += 64){
    int s = cs[k];
    dh += __expf(lrelu(pas[s] + adv) - mh);
  }
  dh = wsum(dh);
  float inv = 1.f / (dh + 1e-16f);

  float acc = 0.f;
  for (int k = beg; k < end; ++k){
    int s = cs[k];
    float e = lrelu(pas[s] + adv);
    float w = __expf(e - mh) * inv;
    acc += w * u16f(xw2[(size_t)s * 64 + lane]);
  }

  float o  = acc + bias2[lane];
  float sc = g2[lane] * rsqrtf(v2[lane] + 1e-5f);
  float res = fmaxf((o - m2[lane]) * sc + b2[lane], 0.f);
  h2[(size_t)n * 64 + lane] = res;
}

// ---- segmented mean pool: one block per graph (batch is sorted)
__global__ __launch_bounds__(256) void k_pool(
    const float* __restrict__ h2, const int* __restrict__ batch,
    float* __restrict__ pool, int N)
{
  int g = blockIdx.x;
  int t = threadIdx.x, c = t & 63, w = t >> 6;
  // lower_bound(batch, g)
  int lo = 0, hi = N;
  while (lo < hi){ int mid = (lo + hi) >> 1; if (batch[mid] < g) lo = mid + 1; else hi = mid; }
  // lower_bound(batch, g+1)
  int lo2 = lo, hi2 = N;
  while (lo2 < hi2){ int mid = (lo2 + hi2) >> 1; if (batch[mid] < g + 1) lo2 = mid + 1; else hi2 = mid; }
  float s = 0.f;
  for (int r = lo + w; r < lo2; r += 4) s += h2[(size_t)r * 64 + c];
  __shared__ float sd[4][64];
  sd[w][c] = s;
  __syncthreads();
  if (w == 0){
    float tot = sd[0][c] + sd[1][c] + sd[2][c] + sd[3][c];
    float cntf = (float)(lo2 - lo);
    pool[g * 64 + c] = tot / fmaxf(cntf, 1.f);
  }
}

// ---- classifier + log_softmax: one wave per graph, fp32 output
__global__ __launch_bounds__(64) void k_final(
    const float* __restrict__ pool,
    const float* __restrict__ Wc1, const float* __restrict__ bc1,
    const float* __restrict__ Wc2, const float* __restrict__ bc2,
    float* __restrict__ out)
{
  int g = blockIdx.x, c = threadIdx.x;
  __shared__ float gr[64];
  gr[c] = pool[g * 64 + c];
  __syncthreads();
  float a = bc1[c];
  for (int k = 0; k < 64; ++k) a += gr[k] * Wc1[k * 64 + c];
  float hc = fmaxf(a, 0.f);
  float p0 = hc * Wc2[c * 2 + 0];
  float p1 = hc * Wc2[c * 2 + 1];
  p0 = wsum(p0); p1 = wsum(p1);
  if (c == 0){
    float l0 = p0 + bc2[0];
    float l1 = p1 + bc2[1];
    float mx = fmaxf(l0, l1);
    float lse = mx + logf(expf(l0 - mx) + expf(l1 - mx));
    out[g * 2 + 0] = l0 - lse;
    out[g * 2 + 1] = l1 - lse;
  }
}

extern "C" void kernel_launch(void* const* d_in, const int* in_sizes, int n_in,
                              void* d_out, int out_size, void* d_ws, size_t ws_size,
                              hipStream_t stream)
{
  const float* x     = (const float*)d_in[0];
  const int*   ei    = (const int*)d_in[1];
  const int*   batch = (const int*)d_in[2];
  const float* W1    = (const float*)d_in[3];
  const float* asrc1 = (const float*)d_in[4];
  const float* adst1 = (const float*)d_in[5];
  const float* bias1 = (const float*)d_in[6];
  const float* bn1g  = (const float*)d_in[7];
  const float* bn1b  = (const float*)d_in[8];
  const float* bn1m  = (const float*)d_in[9];
  const float* bn1v  = (const float*)d_in[10];
  const float* W2    = (const float*)d_in[11];
  const float* asrc2 = (const float*)d_in[12];
  const float* adst2 = (const float*)d_in[13];
  const float* bias2 = (const float*)d_in[14];
  const float* bn2g  = (const float*)d_in[15];
  const float* bn2b  = (const float*)d_in[16];
  const float* bn2m  = (const float*)d_in[17];
  const float* bn2v  = (const float*)d_in[18];
  const float* Wc1   = (const float*)d_in[19];
  const float* bc1   = (const float*)d_in[20];
  const float* Wc2   = (const float*)d_in[21];
  const float* bc2   = (const float*)d_in[22];
  float* out = (float*)d_out;

  const int N  = in_sizes[0] / 128;
  const int E  = in_sizes[1] / 2;
  const int ET = E + N;

  char* p = (char*)d_ws;
  auto take = [&](size_t bytes) -> void* {
    void* q = (void*)p;
    p += ((bytes + 255) & ~(size_t)255);
    return q;
  };
  // zero-initialized region (count + cursor only)
  int*   count  = (int*)  take((size_t)N * 4);
  int*   cursor = (int*)  take((size_t)N * 4);
  size_t zbytes = (size_t)(p - (char*)d_ws);
  float* pool   = (float*)take(64 * 64 * 4);
  int*   ro     = (int*)  take((size_t)(N + 1) * 4);
  int*   bsum   = (int*)  take(1024);
  float* as1    = (float*)take((size_t)N * 16);
  float* ad1    = (float*)take((size_t)N * 16);
  float* as2    = (float*)take((size_t)N * 4);
  float* ad2    = (float*)take((size_t)N * 4);
  unsigned short* xw1 = (unsigned short*)take((size_t)N * 256 * 2);
  unsigned short* h1  = (unsigned short*)take((size_t)N * 256 * 2);
  float* h2     = (float*)take((size_t)N * 64 * 4);
  int*   csr    = (int*)  take((size_t)ET * 4);
  unsigned short* xw2 = xw1;  // alias: xw1 dead after k_edge1, xw2 born in k_gemm2
  (void)count; (void)n_in; (void)ws_size; (void)out_size;

  int zw = (int)(zbytes / 4);
  k_zero<<<dim3((zw + 255) / 256), dim3(256), 0, stream>>>((int*)d_ws, zw);
  k_gemm1<<<dim3((N + 7) / 8), dim3(256), 0, stream>>>(x, W1, asrc1, adst1, xw1, as1, ad1, N);
  k_hist<<<dim3((ET + 255) / 256), dim3(256), 0, stream>>>(ei, count, E, ET);
  int nb = (N + 255) / 256;
  k_scan1<<<dim3(nb), dim3(256), 0, stream>>>(count, ro, bsum, N);
  k_scan2<<<dim3(1), dim3(256), 0, stream>>>(bsum, nb);
  k_scan3<<<dim3(nb), dim3(256), 0, stream>>>(ro, bsum, N, ET);
  k_scatter<<<dim3((ET + 255) / 256), dim3(256), 0, stream>>>(ei, ro, cursor, csr, E, ET);
  k_edge1<<<dim3((N + 3) / 4), dim3(256), 0, stream>>>(ro, csr, xw1, as1, ad1,
                                                       bias1, bn1g, bn1b, bn1m, bn1v, h1, N);
  k_gemm2<<<dim3((N + 31) / 32), dim3(256), 0, stream>>>(h1, W2, asrc2, adst2, xw2, as2, ad2, N);
  k_edge2<<<dim3((N + 3) / 4), dim3(256), 0, stream>>>(ro, csr, xw2, as2, ad2,
                                                       bias2, bn2g, bn2b, bn2m, bn2v, h2, N);
  k_pool<<<dim3(64), dim3(256), 0, stream>>>(h2, batch, pool, N);
  k_final<<<dim3(64), dim3(64), 0, stream>>>(pool, Wc1, bc1, Wc2, bc2, out);
}